// Round 15
// baseline (214.514 us; speedup 1.0000x reference)
//
#include <hip/hip_runtime.h>
#include <cstdint>
#include <cstddef>

typedef int int4v __attribute__((ext_vector_type(4)));
typedef signed char schar;

#define DEVI __device__ __forceinline__

DEVI void load_lds16(const void* g, void* l) {
  __builtin_amdgcn_global_load_lds(
      (const __attribute__((address_space(1))) void*)g,
      (__attribute__((address_space(3))) void*)l, 16, 0, 0);
}

// Bare advisory waits — no sched_barrier, no memory clobber.
#define BAR() __builtin_amdgcn_s_barrier()
#define LGKM(n) asm volatile("s_waitcnt lgkmcnt(" #n ")")
#define VMW(n) asm volatile("s_waitcnt vmcnt(" #n ")")

// ---- pack int32 -> int8, linear (4 elems/thread) ----
__global__ __launch_bounds__(256) void pack_i8(const int* __restrict__ src,
                                               signed char* __restrict__ dst,
                                               int n4) {
  int i = blockIdx.x * 256 + threadIdx.x;
  if (i >= n4) return;
  int4v v = ((const int4v*)src)[i];
  int p = (v.x & 255) | ((v.y & 255) << 8) | ((v.z & 255) << 16) | (v.w << 24);
  ((int*)dst)[i] = p;
}

// ---- pack + transpose: w[K][N] int32 -> wT[N][K] int8, 64x64 LDS tiles ----
__global__ __launch_bounds__(256) void pack_wT(const int* __restrict__ w,
                                               signed char* __restrict__ wT,
                                               int K, int N) {
  __shared__ signed char t[64][68];
  int n0 = blockIdx.x * 64, k0 = blockIdx.y * 64;
  int tr = threadIdx.x >> 6, tc = threadIdx.x & 63;
#pragma unroll
  for (int i = 0; i < 16; ++i) {
    int r = i * 4 + tr;
    t[r][tc] = (signed char)w[(size_t)(k0 + r) * N + n0 + tc];
  }
  __syncthreads();
#pragma unroll
  for (int i = 0; i < 16; ++i) {
    int r = i * 4 + tr;
    wT[(size_t)(n0 + r) * K + k0 + tc] = t[tc][r];
  }
}

// ---- 256x256 4-wave i8 GEMM, 128x128 wave-tile: C = A[M,K]*BT[N,K]^T ----
// 256 threads = 4 waves (2Mx2N), wave-tile 128x128, acc[8][8] = 256 AGPR,
// ~370 total regs -> 1 wave/SIMD (cap 512; no spill expected).
// Arithmetic intensity 64 (vs 32-43 in R2-R14): per 128-B K-tile per CU,
// LDS reads drop 256->128 b128 (1536 cy) + ~600 cy writes < MFMA 2611 cy
// -> FIRST MFMA-dominant geometry. Overlap comes from cross-SIMD skew
// (port is CU-shared, matrix pipes per-SIMD, 4 independent waves).
// BK=128 B (2 K-steps of 16x16x64). LDS 2 bufs x (A 32K + B 32K) = 128 K.
// Simple R5-discipline loop: stage(T+1) at top, compute, lgkm0+vmw0+BAR.
template <int EPI>
__global__ __launch_bounds__(256, 1) void gemmX(
    const schar* __restrict__ A, const schar* __restrict__ BT,
    int M, int N, int K, const int* __restrict__ bias_i,
    const float* __restrict__ alphaP, const float* __restrict__ betaP,
    const float* __restrict__ bias_f, schar* __restrict__ outQ,
    float* __restrict__ outF) {
  extern __shared__ schar lds[];

  const int tid = threadIdx.x;
  const int wid = tid >> 6, lane = tid & 63;
  const int wr = wid >> 1, wc = wid & 1;  // 2M x 2N waves, 128x128 each
  const int l16 = lane & 15, l4 = lane >> 4;

  // XCD-bijective block swizzle (nwg % 8 == 0 for both GEMMs)
  const int gx = gridDim.x;
  const int nwg = gx * gridDim.y;
  const int bid = blockIdx.y * gx + blockIdx.x;
  const int swz = (bid & 7) * (nwg >> 3) + (bid >> 3);
  const int rowBase = (swz / gx) * 256;
  const int colBase = (swz % gx) * 256;
  const int NT = K >> 7;  // 128-B K-tiles (8 or 32)

  const float alpha = alphaP[0];
  const float beta = (EPI == 0) ? betaP[0] : 0.f;
  asm volatile("" ::"s"(alpha), "s"(beta));
  LGKM(0);

  // staging: thread covers o = c*4096 + tid*16, c = 0..7, per 32 KB operand.
  // row rc = c*32 + (tid>>3); slot = tid&7 (chunk-invariant);
  // pre-swizzled source slot gs = (tid&7) ^ ((tid>>3)&7) (chunk-invariant).
  const int strow = tid >> 3;
  const int gs = (tid & 7) ^ (strow & 7);
  const schar* gA0 = A + (size_t)(rowBase + strow) * K + gs * 16;
  const schar* gB0 = BT + (size_t)(colBase + strow) * K + gs * 16;
  const size_t cstep = (size_t)32 * K;  // 32 rows per chunk

  auto stage = [&](int buf, int t) {
    schar* dA = lds + buf * 65536 + wid * 1024;
    schar* dB = dA + 32768;
#pragma unroll
    for (int c = 0; c < 8; ++c)
      load_lds16(gA0 + (size_t)t * 128 + c * cstep, dA + c * 4096);
#pragma unroll
    for (int c = 0; c < 8; ++c)
      load_lds16(gB0 + (size_t)t * 128 + c * cstep, dB + c * 4096);
  };

  // fragment reads: row = base + f*16 + l16 (base mult of 128);
  // slot = (kk*4 + l4) ^ (l16&7) — lane-const per kk.
  const int so0 = ((0 + l4) ^ (l16 & 7)) * 16 + l16 * 128;
  const int so1 = ((4 + l4) ^ (l16 & 7)) * 16 + l16 * 128;
  const int aoff = wr * 16384;           // + f*2048, f=0..7
  const int boff = 32768 + wc * 16384;   // + f*2048

  int4v acc[8][8] = {};
  int4v aF[8], bF[8];

#define RDK(SO, Bu)                                                \
  do {                                                             \
    _Pragma("unroll") for (int f = 0; f < 8; ++f) aF[f] =          \
        *(const int4v*)((Bu) + aoff + f * 2048 + (SO));            \
    _Pragma("unroll") for (int f = 0; f < 8; ++f) bF[f] =          \
        *(const int4v*)((Bu) + boff + f * 2048 + (SO));            \
  } while (0)
#define MMK()                                                          \
  do {                                                                 \
    __builtin_amdgcn_s_setprio(1);                                     \
    _Pragma("unroll") for (int mi = 0; mi < 8; ++mi)                   \
        _Pragma("unroll") for (int ni = 0; ni < 8; ++ni) acc[mi][ni] = \
        __builtin_amdgcn_mfma_i32_16x16x64_i8(aF[mi], bF[ni],          \
                                              acc[mi][ni], 0, 0, 0);   \
    __builtin_amdgcn_s_setprio(0);                                     \
  } while (0)

  // prologue
  stage(0, 0);
  VMW(0);
  BAR();

  for (int T = 0; T < NT; ++T) {
    const schar* Bu = lds + (T & 1) * 65536;

    if (T + 1 < NT) stage((T + 1) & 1, T + 1);  // issue early

    RDK(so0, Bu);
    MMK();  // compiler-counted lgkm waits; reads drain under MFMA issue
    RDK(so1, Bu);
    MMK();

    LGKM(0);  // own reads of this buffer done (WAR vs next staging)
    VMW(0);   // staging landed (issued a full tile earlier)
    BAR();
  }

  // ---- epilogue; C/D frag: col = lane&15, row = (lane>>4)*4 + j ----
  if (EPI == 0) {
#pragma unroll
    for (int MI = 0; MI < 8; ++MI) {
      int row = rowBase + wr * 128 + MI * 16 + l4 * 4;
#pragma unroll
      for (int NI = 0; NI < 8; ++NI) {
        int col = colBase + wc * 128 + NI * 16 + l16;
        float bt = (float)bias_i[col] * beta;
#pragma unroll
        for (int j = 0; j < 4; ++j) {
          float h = (float)acc[MI][NI][j] * alpha + bt;
          h = fmaxf(h, 0.f);
          h = rintf(h);  // numpy round-half-even
          h = fminf(h, 127.f);
          outQ[(size_t)(row + j) * N + col] = (schar)h;
        }
      }
    }
  } else {
#pragma unroll
    for (int MI = 0; MI < 8; ++MI) {
      int row = rowBase + wr * 128 + MI * 16 + l4 * 4;
#pragma unroll
      for (int NI = 0; NI < 8; ++NI) {
        int col = colBase + wc * 128 + NI * 16 + l16;
        float bv = bias_f[col];
#pragma unroll
        for (int j = 0; j < 4; ++j)
          outF[(size_t)(row + j) * N + col] =
              (float)acc[MI][NI][j] * alpha + bv;
      }
    }
  }
#undef RDK
#undef MMK
}

extern "C" void kernel_launch(void* const* d_in, const int* in_sizes, int n_in,
                              void* d_out, int out_size, void* d_ws,
                              size_t ws_size, hipStream_t stream) {
  const int M = 16384, H = 1024, I = 4096;  // B*S = 16384
  const int* hidden = (const int*)d_in[0];
  const int* w_fc = (const int*)d_in[1];
  const int* b_fc = (const int*)d_in[2];
  const float* alpha_fc = (const float*)d_in[3];
  const float* beta_fc = (const float*)d_in[4];
  const int* w_proj = (const int*)d_in[5];
  const float* b_proj = (const float*)d_in[6];
  const float* alpha_proj = (const float*)d_in[7];
  float* out = (float*)d_out;

  signed char* hq = (signed char*)d_ws;     // [M][I]  64 MB
  signed char* aP = hq + (size_t)M * I;     // [M][H]  16 MB
  signed char* wfcT = aP + (size_t)M * H;   // [I][H]   4 MB (w_fc^T)
  signed char* wpT = wfcT + (size_t)I * H;  // [H][I]   4 MB (w_proj^T)

  hipFuncSetAttribute((const void*)gemmX<0>,
                      hipFuncAttributeMaxDynamicSharedMemorySize, 131072);
  hipFuncSetAttribute((const void*)gemmX<1>,
                      hipFuncAttributeMaxDynamicSharedMemorySize, 131072);

  pack_i8<<<(M * H / 4 + 255) / 256, 256, 0, stream>>>(hidden, aP, M * H / 4);
  pack_wT<<<dim3(I / 64, H / 64), 256, 0, stream>>>(w_fc, wfcT, H, I);
  pack_wT<<<dim3(H / 64, I / 64), 256, 0, stream>>>(w_proj, wpT, I, H);

  gemmX<0><<<dim3(I / 256, M / 256), 256, 131072, stream>>>(
      aP, wfcT, M, I, H, b_fc, alpha_fc, beta_fc, nullptr, hq, nullptr);
  gemmX<1><<<dim3(H / 256, M / 256), 256, 131072, stream>>>(
      hq, wpT, M, H, I, nullptr, alpha_proj, nullptr, b_proj, nullptr, out);
}

// Round 16
// 175.950 us; speedup vs baseline: 1.2192x; 1.2192x over previous
//
#include <hip/hip_runtime.h>
#include <cstdint>
#include <cstddef>

typedef int int4v __attribute__((ext_vector_type(4)));
typedef signed char schar;

#define DEVI __device__ __forceinline__

DEVI void load_lds16(const void* g, void* l) {
  __builtin_amdgcn_global_load_lds(
      (const __attribute__((address_space(1))) void*)g,
      (__attribute__((address_space(3))) void*)l, 16, 0, 0);
}

// Bare advisory waits — no sched_barrier, no memory clobber.
#define BAR() __builtin_amdgcn_s_barrier()
#define LGKM(n) asm volatile("s_waitcnt lgkmcnt(" #n ")")
#define VMW(n) asm volatile("s_waitcnt vmcnt(" #n ")")

// ---- pack int32 -> int8, linear (4 elems/thread) ----
__global__ __launch_bounds__(256) void pack_i8(const int* __restrict__ src,
                                               signed char* __restrict__ dst,
                                               int n4) {
  int i = blockIdx.x * 256 + threadIdx.x;
  if (i >= n4) return;
  int4v v = ((const int4v*)src)[i];
  int p = (v.x & 255) | ((v.y & 255) << 8) | ((v.z & 255) << 16) | (v.w << 24);
  ((int*)dst)[i] = p;
}

// ---- pack + transpose: w[K][N] int32 -> wT[N][K] int8, 64x64 LDS tiles ----
__global__ __launch_bounds__(256) void pack_wT(const int* __restrict__ w,
                                               signed char* __restrict__ wT,
                                               int K, int N) {
  __shared__ signed char t[64][68];
  int n0 = blockIdx.x * 64, k0 = blockIdx.y * 64;
  int tr = threadIdx.x >> 6, tc = threadIdx.x & 63;
#pragma unroll
  for (int i = 0; i < 16; ++i) {
    int r = i * 4 + tr;
    t[r][tc] = (signed char)w[(size_t)(k0 + r) * N + n0 + tc];
  }
  __syncthreads();
#pragma unroll
  for (int i = 0; i < 16; ++i) {
    int r = i * 4 + tr;
    wT[(size_t)(n0 + r) * K + k0 + tc] = t[tc][r];
  }
}

// ---- 256x256 i8 GEMM (R5 base, de-poisoned): C = A[M,K] * BT[N,K]^T ----
// 8 waves (2Mx4N), 128x64 out/wave, acc[8][4]=128 AGPR, ~120 VGPR.
// BK=128 B (2 K-steps of 16x16x64), 2 LDS buffers (128 KiB).
// Per tile: stage(T+1) first; read B k0+k1 into SEPARATE reg sets and A k0;
// MFMA k0 (compiler-counted lgkm waits interleave the drain under issue);
// read A k1 (aF reuse, WAR vs k0 MFMA issues); MFMA k1 (B already in regs
// -> no B wait at the k-boundary); single lgkm(0)+vmcnt(0)+BAR.
// No setprio (measured null-to-negative on non-8-phase GEMM, m190).
// No mid-tile forced drains (the R2-R14 convoy poison).
template <int EPI>
__global__ __launch_bounds__(512, 2) void gemmZ(
    const schar* __restrict__ A, const schar* __restrict__ BT,
    int M, int N, int K, const int* __restrict__ bias_i,
    const float* __restrict__ alphaP, const float* __restrict__ betaP,
    const float* __restrict__ bias_f, schar* __restrict__ outQ,
    float* __restrict__ outF) {
  extern __shared__ schar lds[];

  const int tid = threadIdx.x;
  const int wid = tid >> 6, lane = tid & 63;
  const int wr = wid >> 2, wc = wid & 3;  // 2M x 4N waves
  const int l16 = lane & 15, l4 = lane >> 4;

  // XCD-bijective block swizzle (nwg % 8 == 0 for both GEMMs)
  const int gx = gridDim.x;
  const int nwg = gx * gridDim.y;
  const int bid = blockIdx.y * gx + blockIdx.x;
  const int swz = (bid & 7) * (nwg >> 3) + (bid >> 3);
  const int rowBase = (swz / gx) * 256;
  const int colBase = (swz % gx) * 256;
  const int NT = K >> 7;

  const float alpha = alphaP[0];
  const float beta = (EPI == 0) ? betaP[0] : 0.f;
  asm volatile("" ::"s"(alpha), "s"(beta));
  LGKM(0);

  // staging source pointers (pre-swizzled global slot; LDS dest linear)
  const schar* gA[4];
  const schar* gB[4];
#pragma unroll
  for (int c = 0; c < 4; ++c) {
    int off = c * 8192 + tid * 16;
    int r = off >> 7;
    int gs = ((off >> 4) & 7) ^ (r & 7);
    gA[c] = A + (size_t)(rowBase + r) * K + gs * 16;
    gB[c] = BT + (size_t)(colBase + r) * K + gs * 16;
  }

  auto stage = [&](int buf, int t) {
#pragma unroll
    for (int c = 0; c < 4; ++c)
      load_lds16(gA[c] + (size_t)t * 128,
                 lds + buf * 32768 + c * 8192 + wid * 1024);
#pragma unroll
    for (int c = 0; c < 4; ++c)
      load_lds16(gB[c] + (size_t)t * 128,
                 lds + 65536 + buf * 32768 + c * 8192 + wid * 1024);
  };

  // fragment read offsets; row&7 == l16&7 so swizzle slot is lane-const
  const int so0 = ((0 + l4) ^ (l16 & 7)) * 16 + l16 * 128;  // kk=0
  const int so1 = ((4 + l4) ^ (l16 & 7)) * 16 + l16 * 128;  // kk=1

  int4v acc[8][4] = {};
  int4v aF[8], bF0[4], bF1[4];

#define RDA(SO, Ab)                                                  \
  _Pragma("unroll") for (int mi = 0; mi < 8; ++mi) aF[mi] =          \
      *(const int4v*)((Ab) + wr * 16384 + mi * 2048 + (SO))
#define RDB(DST, SO, Bb)                                             \
  _Pragma("unroll") for (int ni = 0; ni < 4; ++ni) (DST)[ni] =       \
      *(const int4v*)((Bb) + wc * 8192 + ni * 2048 + (SO))
#define MMALL(BF)                                                      \
  _Pragma("unroll") for (int mi = 0; mi < 8; ++mi)                     \
      _Pragma("unroll") for (int ni = 0; ni < 4; ++ni) acc[mi][ni] =   \
      __builtin_amdgcn_mfma_i32_16x16x64_i8(aF[mi], (BF)[ni],          \
                                            acc[mi][ni], 0, 0, 0)

  // prologue: stage tile 0, drain, barrier
  stage(0, 0);
  VMW(0);
  BAR();

  for (int T = 0; T < NT; ++T) {
    const int cb = T & 1, ob = cb ^ 1;
    const schar* Ab = lds + cb * 32768;
    const schar* Bb = lds + 65536 + cb * 32768;

    if (T + 1 < NT) stage(ob, T + 1);  // earliest VMEM entry

    // B both k-steps up-front (separate regs), then A k0.
    RDB(bF0, so0, Bb);
    RDB(bF1, so1, Bb);
    RDA(so0, Ab);
    MMALL(bF0);  // compiler-counted lgkm waits: drain interleaves w/ issue
    // A k1 (aF reuse; WAR ordered vs k0 MFMA issues by scoreboard)
    RDA(so1, Ab);
    MMALL(bF1);  // B already resident -> only A-reads gate this phase

    LGKM(0);  // all reads of buffer cb done before leaving tile (WAR)
    VMW(0);   // own staging landed (issued a full tile earlier)
    BAR();    // publish buffer ob
  }

  // ---- epilogue; C/D frag: col = lane&15, row = (lane>>4)*4 + j ----
  if (EPI == 0) {
#pragma unroll
    for (int MI = 0; MI < 8; ++MI) {
      int row = rowBase + wr * 128 + MI * 16 + l4 * 4;
#pragma unroll
      for (int NI = 0; NI < 4; ++NI) {
        int col = colBase + wc * 64 + NI * 16 + l16;
        float bt = (float)bias_i[col] * beta;
#pragma unroll
        for (int j = 0; j < 4; ++j) {
          float h = (float)acc[MI][NI][j] * alpha + bt;
          h = fmaxf(h, 0.f);
          h = rintf(h);  // numpy round-half-even
          h = fminf(h, 127.f);
          outQ[(size_t)(row + j) * N + col] = (schar)h;
        }
      }
    }
  } else {
#pragma unroll
    for (int MI = 0; MI < 8; ++MI) {
      int row = rowBase + wr * 128 + MI * 16 + l4 * 4;
#pragma unroll
      for (int NI = 0; NI < 4; ++NI) {
        int col = colBase + wc * 64 + NI * 16 + l16;
        float bv = bias_f[col];
#pragma unroll
        for (int j = 0; j < 4; ++j)
          outF[(size_t)(row + j) * N + col] =
              (float)acc[MI][NI][j] * alpha + bv;
      }
    }
  }
#undef RDA
#undef RDB
#undef MMALL
}

extern "C" void kernel_launch(void* const* d_in, const int* in_sizes, int n_in,
                              void* d_out, int out_size, void* d_ws,
                              size_t ws_size, hipStream_t stream) {
  const int M = 16384, H = 1024, I = 4096;  // B*S = 16384
  const int* hidden = (const int*)d_in[0];
  const int* w_fc = (const int*)d_in[1];
  const int* b_fc = (const int*)d_in[2];
  const float* alpha_fc = (const float*)d_in[3];
  const float* beta_fc = (const float*)d_in[4];
  const int* w_proj = (const int*)d_in[5];
  const float* b_proj = (const float*)d_in[6];
  const float* alpha_proj = (const float*)d_in[7];
  float* out = (float*)d_out;

  signed char* hq = (signed char*)d_ws;     // [M][I]  64 MB
  signed char* aP = hq + (size_t)M * I;     // [M][H]  16 MB
  signed char* wfcT = aP + (size_t)M * H;   // [I][H]   4 MB (w_fc^T)
  signed char* wpT = wfcT + (size_t)I * H;  // [H][I]   4 MB (w_proj^T)

  hipFuncSetAttribute((const void*)gemmZ<0>,
                      hipFuncAttributeMaxDynamicSharedMemorySize, 131072);
  hipFuncSetAttribute((const void*)gemmZ<1>,
                      hipFuncAttributeMaxDynamicSharedMemorySize, 131072);

  pack_i8<<<(M * H / 4 + 255) / 256, 256, 0, stream>>>(hidden, aP, M * H / 4);
  pack_wT<<<dim3(I / 64, H / 64), 256, 0, stream>>>(w_fc, wfcT, H, I);
  pack_wT<<<dim3(H / 64, I / 64), 256, 0, stream>>>(w_proj, wpT, I, H);

  gemmZ<0><<<dim3(I / 256, M / 256), 512, 131072, stream>>>(
      aP, wfcT, M, I, H, b_fc, alpha_fc, beta_fc, nullptr, hq, nullptr);
  gemmZ<1><<<dim3(H / 256, M / 256), 512, 131072, stream>>>(
      hq, wpT, M, H, I, nullptr, alpha_proj, nullptr, b_proj, nullptr, out);
}